// Round 12
// baseline (314.219 us; speedup 1.0000x reference)
//
#include <hip/hip_runtime.h>
#include <hip/hip_bf16.h>

typedef __hip_bfloat16 bf16;

static constexpr int N_NODES = 100000;
static constexpr int N_EDGES = 3200000;
static constexpr int F_IN    = 54;
static constexpr int F_HID   = 16;

// bucket/CSR path
static constexpr int BSHIFT    = 7;                  // 128 nodes per bucket
static constexpr int BNODES    = 128;
static constexpr int NBUCK     = (N_NODES + BNODES - 1) / BNODES;  // 782
static constexpr int CAP_B     = 5120;
static constexpr int BIN_CHUNK = 8192;
static constexpr int GRDB      = (N_EDGES + BIN_CHUNK - 1) / BIN_CHUNK;  // 391
static constexpr int GRDN_F    = (N_NODES + 1023) / 1024;                // 98

// ---------------------------------------------------------------------------
// ws layout (float indices) — identical to round-11 (proven).
// hc1/hc2: combined per-node 64-B rows, dword k = bf16(h[k]) | bf16(a_src)<<16.
// srcs now stores BYTE offsets (src*64) so gather addr = lane_base + off.
// ---------------------------------------------------------------------------
static constexpr size_t WS_FLAGS  = 0;        // 4 ints
static constexpr size_t WS_ADST   = 4;        // 100000
static constexpr size_t WS_ADST2  = 100004;   // 100000
static constexpr size_t WS_BCNT   = 200004;   // 1024 ints
static constexpr size_t WS_ROWBEG = 201028;   // 100000 ints
static constexpr size_t WS_ROWCNT = 301028;   // 100000 ints
static constexpr size_t WS_HC1    = 401028;   // 1,600,000 dw
static constexpr size_t WS_HC2    = 2001028;  // 1,600,000 dw
static constexpr size_t WS_BEDGES = 3601028;  // NBUCK*CAP_B ints
static constexpr size_t WS_SRCS   = 7604868;  // NBUCK*CAP_B ints
static constexpr size_t WS_BUCKET_END = WS_SRCS + (size_t)NBUCK * CAP_B; // 11,608,708
static constexpr size_t WS_FB_DEN     = 3601028;
static constexpr size_t WS_FB_AS      = 3701028;
static constexpr size_t WS_ATOMIC_END = 3801028;

__device__ __forceinline__ float lrelu(float v) { return fmaxf(v, 0.2f * v); }
__device__ __forceinline__ float loadf(const void* p, int i, bool f32) {
    return f32 ? ((const float*)p)[i] : __bfloat162float(((const bf16*)p)[i]);
}
__device__ __forceinline__ unsigned f2bf(float f) {   // RNE fp32->bf16 bits
    unsigned u = __float_as_uint(f);
    return (u + 0x7FFFu + ((u >> 16) & 1u)) >> 16;
}

// ---------------------------------------------------------------------------
// Probe (+ zero bcnt): bit0 = floats fp32 ; bit1 = edge_index int64
// ---------------------------------------------------------------------------
__global__ __launch_bounds__(256) void k_probe0(
    const void* __restrict__ x, const void* __restrict__ ei,
    int* __restrict__ flags, int* __restrict__ bcnt)
{
    __shared__ int cnt, nz;
    const int t = threadIdx.x;
    if (t == 0) { cnt = 0; nz = 0; }
    __syncthreads();
    const unsigned u = ((const unsigned*)x)[t];
    if ((u & 0x7FFFu) >= 0x4800u) atomicAdd(&cnt, 1);
    if (t < 64) {
        if (((const unsigned*)ei)[2 * t + 1] != 0u) atomicAdd(&nz, 1);
    }
    for (int i = t; i < 1024; i += 256) bcnt[i] = 0;
    __syncthreads();
    if (t == 0) flags[0] = ((cnt >= 16) ? 1 : 0) | ((nz == 0) ? 2 : 0);
}

// ---------------------------------------------------------------------------
// k_binfeat (1024 thr): [0,GRDB) bin w/ LDS edge cache; [GRDB,+GRDN_F) feat1:
// h1 = x@W1 (fp32 regs); emits combined row dword k = bf16(h[k])|bf16(a)<<16.
// ---------------------------------------------------------------------------
__global__ __launch_bounds__(1024, 8) void k_binfeat(
    const void* __restrict__ ei, const void* __restrict__ x,
    const void* __restrict__ W1, const void* __restrict__ a_s,
    const void* __restrict__ a_d, const int* __restrict__ flags,
    int* __restrict__ bcnt, int* __restrict__ bedges,
    unsigned* __restrict__ hc, float* __restrict__ adst)
{
    __shared__ int            hist[NBUCK];
    __shared__ int            base[NBUCK];
    __shared__ int            cval[BIN_CHUNK];
    __shared__ unsigned short cbkt[BIN_CHUNK];
    __shared__ float Wl[F_IN * F_HID];
    __shared__ float asl[F_HID];
    __shared__ float adl[F_HID];
    const int t = threadIdx.x;
    const bool f32 = flags[0] & 1;
    const bool i64 = flags[0] & 2;

    if (blockIdx.x < GRDB) {
        const int e0 = blockIdx.x * BIN_CHUNK;
        const int valid = min(BIN_CHUNK, N_EDGES - e0);
        for (int i = t; i < NBUCK; i += 1024) hist[i] = 0;
        __syncthreads();
#pragma unroll
        for (int i = 0; i < BIN_CHUNK / 1024; ++i) {
            const int idx = i * 1024 + t;
            const int e = e0 + idx;
            if (idx < valid) {
                int s, d;
                if (i64) {
                    s = ((const int*)ei)[2 * (size_t)e];
                    d = ((const int*)ei)[2 * ((size_t)N_EDGES + e)];
                } else {
                    s = ((const int*)ei)[e];
                    d = ((const int*)ei)[(size_t)N_EDGES + e];
                }
                const int b = d >> BSHIFT;
                cval[idx] = (s << BSHIFT) | (d & (BNODES - 1));
                cbkt[idx] = (unsigned short)b;
                atomicAdd(&hist[b], 1);
            }
        }
        __syncthreads();
        for (int i = t; i < NBUCK; i += 1024) {
            const int c = hist[i];
            base[i] = c ? atomicAdd(&bcnt[i], c) : 0;
            hist[i] = 0;
        }
        __syncthreads();
#pragma unroll
        for (int i = 0; i < BIN_CHUNK / 1024; ++i) {
            const int idx = i * 1024 + t;
            if (idx < valid) {
                const int b = cbkt[idx];
                const int r = atomicAdd(&hist[b], 1);
                const int pos = base[b] + r;
                if (pos < CAP_B) bedges[(size_t)b * CAP_B + pos] = cval[idx];
            }
        }
    } else {
        for (int i = t; i < F_IN * F_HID; i += 1024) Wl[i] = loadf(W1, i, f32);
        if (t < F_HID) { asl[t] = loadf(a_s, t, f32); adl[t] = loadf(a_d, t, f32); }
        __syncthreads();
        const int node = (blockIdx.x - GRDB) * 1024 + t;
        if (node >= N_NODES) return;

        float h[F_HID];
#pragma unroll
        for (int k = 0; k < F_HID; ++k) h[k] = 0.f;
        if (f32) {
            const float2* xp = (const float2*)((const float*)x + (size_t)node * F_IN);
#pragma unroll
            for (int j = 0; j < F_IN / 2; ++j) {
                const float2 v = xp[j];
#pragma unroll
                for (int k = 0; k < F_HID; ++k) {
                    h[k] = fmaf(v.x, Wl[(2*j)   * F_HID + k], h[k]);
                    h[k] = fmaf(v.y, Wl[(2*j+1) * F_HID + k], h[k]);
                }
            }
        } else {
            const unsigned* xu = (const unsigned*)x + (size_t)node * (F_IN / 2);
#pragma unroll
            for (int j = 0; j < F_IN / 2; ++j) {
                const unsigned u = xu[j];
                const float v0 = __uint_as_float(u << 16);
                const float v1 = __uint_as_float(u & 0xFFFF0000u);
#pragma unroll
                for (int k = 0; k < F_HID; ++k) {
                    h[k] = fmaf(v0, Wl[(2*j)   * F_HID + k], h[k]);
                    h[k] = fmaf(v1, Wl[(2*j+1) * F_HID + k], h[k]);
                }
            }
        }
        float s = 0.f, d = 0.f;
#pragma unroll
        for (int k = 0; k < F_HID; ++k) { s = fmaf(h[k], asl[k], s); d = fmaf(h[k], adl[k], d); }
        adst[node] = d;
        const unsigned ab = f2bf(s) << 16;
        unsigned pk[F_HID];
#pragma unroll
        for (int k = 0; k < F_HID; ++k) pk[k] = f2bf(h[k]) | ab;
        uint4* hb = (uint4*)(hc + (size_t)node * F_HID);
#pragma unroll
        for (int q = 0; q < 4; ++q)
            hb[q] = make_uint4(pk[4*q], pk[4*q+1], pk[4*q+2], pk[4*q+3]);
    }
}

// ---------------------------------------------------------------------------
// k_bsort (512 thr): per-bucket LDS counting sort into 16B-padded segments.
// srcs entries are pre-scaled BYTE offsets (src * 64) for cheap agg addressing.
// ---------------------------------------------------------------------------
__global__ __launch_bounds__(512) void k_bsort(
    const int* __restrict__ bcnt, const int* __restrict__ bedges,
    int* __restrict__ rowbeg, int* __restrict__ rowcnt, int* __restrict__ srcs)
{
    __shared__ int hist[BNODES];
    __shared__ int scan[BNODES];
    __shared__ int cur[BNODES];
    const int t = threadIdx.x;
    const int b = blockIdx.x;
    const int n0 = b << BSHIFT;
    if (t < BNODES) hist[t] = 0;
    __syncthreads();
    const int cnt = min(bcnt[b], CAP_B);
    const int* be = bedges + (size_t)b * CAP_B;
    for (int e = t; e < cnt; e += 512)
        atomicAdd(&hist[be[e] & (BNODES - 1)], 1);
    __syncthreads();
    if (t < BNODES) scan[t] = (hist[t] + 3) & ~3;
    __syncthreads();
#pragma unroll
    for (int off = 1; off < BNODES; off <<= 1) {
        const int v = (t < BNODES && t >= off) ? scan[t - off] : 0;
        __syncthreads();
        if (t < BNODES) scan[t] += v;
        __syncthreads();
    }
    if (t < BNODES) {
        const int ex = scan[t] - ((hist[t] + 3) & ~3);
        cur[t] = ex;
        const int node = n0 + t;
        if (node < N_NODES) {
            rowbeg[node] = b * CAP_B + ex;
            rowcnt[node] = hist[t];
        }
    }
    __syncthreads();
    for (int e = t; e < cnt; e += 512) {
        const int p = be[e];
        const int dl = p & (BNODES - 1);
        const int r = atomicAdd(&cur[dl], 1);
        if (r < CAP_B) srcs[(size_t)b * CAP_B + r] = (p >> BSHIFT) << 6;  // byte off
    }
}

// ---------------------------------------------------------------------------
// k_agg1: 16 lanes/node. 16-edge unroll: lane k loads srcs[i+k] (coalesced),
// computes ONLY its own edge's weight (1 exp per 16 edges/lane), distributes
// offsets+weights via width-16 shuffles; 16 one-dword gathers in flight.
// Epilogue fuses mid (z@W2 via shuffles) and emits the layer-2 combined row.
// ---------------------------------------------------------------------------
__global__ __launch_bounds__(256) void k_agg1(
    const int* __restrict__ rowbeg, const int* __restrict__ rowcnt,
    const int* __restrict__ srcs, const float* __restrict__ adst,
    const unsigned* __restrict__ hc, const void* __restrict__ b1,
    const void* __restrict__ W2, const void* __restrict__ a_s2,
    const void* __restrict__ a_d2, const int* __restrict__ flags,
    unsigned* __restrict__ hc2, float* __restrict__ adst2)
{
    __shared__ float Wl[F_HID * F_HID];
    __shared__ float asl[F_HID];
    __shared__ float adl[F_HID];
    __shared__ float bl[F_HID];
    const bool f32 = flags[0] & 1;
    const int t = threadIdx.x;
    if (t < F_HID * F_HID) Wl[t] = loadf(W2, t, f32);
    if (t < F_HID) {
        asl[t] = loadf(a_s2, t, f32);
        adl[t] = loadf(a_d2, t, f32);
        bl[t]  = loadf(b1, t, f32);
    }
    __syncthreads();

    const int k = t & 15;
    const int node = blockIdx.x * 16 + (t >> 4);       // 6250*16 = 100000 exact
    const float adn = adst[node];
    const char* hcb = (const char*)hc + 4 * k;          // lane base (loop-invariant)
    const unsigned vs = hc[(size_t)node * F_HID + k];
    const float w0 = __expf(lrelu(__uint_as_float(vs & 0xFFFF0000u) + adn));
    float denom = w0;
    float acc = w0 * __uint_as_float(vs << 16);
    const int n = rowcnt[node];
    const int* sp = srcs + rowbeg[node];
    int i = 0;
    for (; i + 16 <= n; i += 16) {
        const unsigned off = (unsigned)sp[i + k];                       // per-lane
        const unsigned vown = *(const unsigned*)(hcb + off);            // own row dword k
        const float eo = __expf(lrelu(__uint_as_float(vown & 0xFFFF0000u) + adn));
#pragma unroll
        for (int m = 0; m < 16; ++m) {
            const unsigned om = (unsigned)__shfl((int)off, m, 16);
            const float   em = __shfl(eo, m, 16);
            const unsigned v = *(const unsigned*)(hcb + om);
            denom += em;
            acc = fmaf(em, __uint_as_float(v << 16), acc);
        }
    }
    for (; i < n; ++i) {
        const unsigned off = (unsigned)sp[i];                            // broadcast
        const unsigned v = *(const unsigned*)(hcb + off);
        const float w = __expf(lrelu(__uint_as_float(v & 0xFFFF0000u) + adn));
        denom += w;
        acc = fmaf(w, __uint_as_float(v << 16), acc);
    }
    float z = acc / denom + bl[k];
    z = z > 0.f ? z : expm1f(z);

    float hh = 0.f;
#pragma unroll
    for (int j = 0; j < F_HID; ++j) {
        const float zj = __shfl(z, j, 16);
        hh = fmaf(zj, Wl[j * F_HID + k], hh);
    }
    float s2 = hh * asl[k], d2 = hh * adl[k];
#pragma unroll
    for (int off = 1; off < 16; off <<= 1) {
        s2 += __shfl_xor(s2, off, 16);
        d2 += __shfl_xor(d2, off, 16);
    }
    hc2[(size_t)node * F_HID + k] = f2bf(hh) | (f2bf(s2) << 16);
    if (k == 0) adst2[node] = d2;
}

// ---------------------------------------------------------------------------
// k_agg2: same dedup-weight gather on layer-2 rows; writes fp32 out.
// ---------------------------------------------------------------------------
__global__ __launch_bounds__(256) void k_agg2(
    const int* __restrict__ rowbeg, const int* __restrict__ rowcnt,
    const int* __restrict__ srcs, const float* __restrict__ adst,
    const unsigned* __restrict__ hc, const void* __restrict__ b2,
    const int* __restrict__ flags, float* __restrict__ outp)
{
    const bool f32 = flags[0] & 1;
    const int t = threadIdx.x;
    const int k = t & 15;
    const int node = blockIdx.x * 16 + (t >> 4);
    const float adn = adst[node];
    const char* hcb = (const char*)hc + 4 * k;
    const unsigned vs = hc[(size_t)node * F_HID + k];
    const float w0 = __expf(lrelu(__uint_as_float(vs & 0xFFFF0000u) + adn));
    float denom = w0;
    float acc = w0 * __uint_as_float(vs << 16);
    const int n = rowcnt[node];
    const int* sp = srcs + rowbeg[node];
    int i = 0;
    for (; i + 16 <= n; i += 16) {
        const unsigned off = (unsigned)sp[i + k];
        const unsigned vown = *(const unsigned*)(hcb + off);
        const float eo = __expf(lrelu(__uint_as_float(vown & 0xFFFF0000u) + adn));
#pragma unroll
        for (int m = 0; m < 16; ++m) {
            const unsigned om = (unsigned)__shfl((int)off, m, 16);
            const float   em = __shfl(eo, m, 16);
            const unsigned v = *(const unsigned*)(hcb + om);
            denom += em;
            acc = fmaf(em, __uint_as_float(v << 16), acc);
        }
    }
    for (; i < n; ++i) {
        const unsigned off = (unsigned)sp[i];
        const unsigned v = *(const unsigned*)(hcb + off);
        const float w = __expf(lrelu(__uint_as_float(v & 0xFFFF0000u) + adn));
        denom += w;
        acc = fmaf(w, __uint_as_float(v << 16), acc);
    }
    outp[(size_t)node * F_HID + k] = acc / denom + loadf(b2, k, f32);
}

// ---------------------------------------------------------------------------
// Fallback kernels (round-3 proven atomic path, fp32 buffers) + diag
// ---------------------------------------------------------------------------
__global__ __launch_bounds__(256) void k_feat1(
    const void* __restrict__ x, const void* __restrict__ W1,
    const void* __restrict__ a_s, const void* __restrict__ a_d,
    const int* __restrict__ flags,
    float* __restrict__ hbuf, float* __restrict__ asrc, float* __restrict__ adst)
{
    const bool f32 = flags[0] & 1;
    __shared__ float Wl[F_IN * F_HID];
    __shared__ float asl[F_HID];
    __shared__ float adl[F_HID];
    const int t = threadIdx.x;
    for (int i = t; i < F_IN * F_HID; i += 256) Wl[i] = loadf(W1, i, f32);
    if (t < F_HID) { asl[t] = loadf(a_s, t, f32); adl[t] = loadf(a_d, t, f32); }
    __syncthreads();
    const int node = blockIdx.x * 256 + t;
    if (node >= N_NODES) return;
    float h[F_HID];
#pragma unroll
    for (int k = 0; k < F_HID; ++k) h[k] = 0.f;
    if (f32) {
        const float2* xp = (const float2*)((const float*)x + (size_t)node * F_IN);
#pragma unroll
        for (int j = 0; j < F_IN / 2; ++j) {
            const float2 v = xp[j];
#pragma unroll
            for (int k = 0; k < F_HID; ++k) {
                h[k] = fmaf(v.x, Wl[(2*j)   * F_HID + k], h[k]);
                h[k] = fmaf(v.y, Wl[(2*j+1) * F_HID + k], h[k]);
            }
        }
    } else {
        const unsigned* xu = (const unsigned*)x + (size_t)node * (F_IN / 2);
#pragma unroll
        for (int j = 0; j < F_IN / 2; ++j) {
            const unsigned u = xu[j];
            const float v0 = __uint_as_float(u << 16);
            const float v1 = __uint_as_float(u & 0xFFFF0000u);
#pragma unroll
            for (int k = 0; k < F_HID; ++k) {
                h[k] = fmaf(v0, Wl[(2*j)   * F_HID + k], h[k]);
                h[k] = fmaf(v1, Wl[(2*j+1) * F_HID + k], h[k]);
            }
        }
    }
    float s = 0.f, d = 0.f;
#pragma unroll
    for (int k = 0; k < F_HID; ++k) { s = fmaf(h[k], asl[k], s); d = fmaf(h[k], adl[k], d); }
    asrc[node] = s; adst[node] = d;
    float4* hb = (float4*)(hbuf + (size_t)node * F_HID);
#pragma unroll
    for (int q = 0; q < 4; ++q)
        hb[q] = make_float4(h[4*q], h[4*q+1], h[4*q+2], h[4*q+3]);
}

__global__ __launch_bounds__(256) void k_selfinit(
    const float* __restrict__ asrc, const float* __restrict__ adst,
    const float* __restrict__ h, float* __restrict__ denom, float* __restrict__ acc)
{
    const int t = blockIdx.x * 256 + threadIdx.x;
    if (t >= N_NODES * F_HID) return;
    const int n = t >> 4;
    const float w0 = __expf(lrelu(asrc[n] + adst[n]));
    if ((t & 15) == 0) denom[n] = w0;
    acc[t] = w0 * h[t];
}

__global__ __launch_bounds__(256) void k_edge(
    const void* __restrict__ ei, const int* __restrict__ flags,
    const float* __restrict__ asrc, const float* __restrict__ adst,
    const float* __restrict__ hbuf,
    float* __restrict__ denom, float* __restrict__ acc)
{
    const int e = blockIdx.x * 256 + threadIdx.x;
    if (e >= N_EDGES) return;
    int s, d;
    if (flags[0] & 2) {
        const long long* e64 = (const long long*)ei;
        s = (int)e64[e]; d = (int)e64[(size_t)N_EDGES + e];
    } else {
        const int* e32 = (const int*)ei;
        s = e32[e]; d = e32[(size_t)N_EDGES + e];
    }
    const float w = __expf(lrelu(asrc[s] + adst[d]));
    atomicAdd(&denom[d], w);
    const float4* hs = (const float4*)(hbuf + (size_t)s * F_HID);
    float* ad = acc + (size_t)d * F_HID;
#pragma unroll
    for (int q = 0; q < 4; ++q) {
        const float4 hv = hs[q];
        atomicAdd(ad + 4*q + 0, w * hv.x);
        atomicAdd(ad + 4*q + 1, w * hv.y);
        atomicAdd(ad + 4*q + 2, w * hv.z);
        atomicAdd(ad + 4*q + 3, w * hv.w);
    }
}

__global__ __launch_bounds__(256) void k_div_elu(
    float* __restrict__ acc, const float* __restrict__ denom,
    const void* __restrict__ b1, const int* __restrict__ flags)
{
    const bool f32 = flags[0] & 1;
    const int t = blockIdx.x * 256 + threadIdx.x;
    if (t >= N_NODES * F_HID) return;
    const float v = acc[t] / denom[t >> 4] + loadf(b1, t & 15, f32);
    acc[t] = v > 0.f ? v : expm1f(v);
}

__global__ __launch_bounds__(256) void k_mid(
    const float* __restrict__ z,
    const void* __restrict__ W2, const void* __restrict__ a_s2,
    const void* __restrict__ a_d2, const int* __restrict__ flags,
    float* __restrict__ h2, float* __restrict__ asrc, float* __restrict__ adst)
{
    const bool f32 = flags[0] & 1;
    __shared__ float Wl[F_HID * F_HID];
    __shared__ float asl[F_HID];
    __shared__ float adl[F_HID];
    const int t = threadIdx.x;
    if (t < F_HID * F_HID) Wl[t] = loadf(W2, t, f32);
    if (t < F_HID) { asl[t] = loadf(a_s2, t, f32); adl[t] = loadf(a_d2, t, f32); }
    __syncthreads();
    const int node = blockIdx.x * 256 + t;
    if (node >= N_NODES) return;
    float zr[F_HID];
    const float4* zi = (const float4*)(z + (size_t)node * F_HID);
#pragma unroll
    for (int q = 0; q < 4; ++q) {
        const float4 zv = zi[q];
        zr[4*q+0]=zv.x; zr[4*q+1]=zv.y; zr[4*q+2]=zv.z; zr[4*q+3]=zv.w;
    }
    float h[F_HID];
#pragma unroll
    for (int k = 0; k < F_HID; ++k) h[k] = 0.f;
#pragma unroll
    for (int j = 0; j < F_HID; ++j) {
        const float zv = zr[j];
#pragma unroll
        for (int k = 0; k < F_HID; ++k) h[k] = fmaf(zv, Wl[j * F_HID + k], h[k]);
    }
    float s = 0.f, d = 0.f;
#pragma unroll
    for (int k = 0; k < F_HID; ++k) { s = fmaf(h[k], asl[k], s); d = fmaf(h[k], adl[k], d); }
    asrc[node] = s; adst[node] = d;
    float4* hb = (float4*)(h2 + (size_t)node * F_HID);
#pragma unroll
    for (int q = 0; q < 4; ++q)
        hb[q] = make_float4(h[4*q], h[4*q+1], h[4*q+2], h[4*q+3]);
}

__global__ __launch_bounds__(256) void k_out(
    const float* __restrict__ acc, const float* __restrict__ denom,
    const void* __restrict__ b2, const int* __restrict__ flags,
    float* __restrict__ out)
{
    const bool f32 = flags[0] & 1;
    const int t = blockIdx.x * 256 + threadIdx.x;
    if (t >= N_NODES * F_HID) return;
    out[t] = acc[t] / denom[t >> 4] + loadf(b2, t & 15, f32);
}

__global__ __launch_bounds__(256) void k_diag(float* __restrict__ out, float v)
{
    const int t = blockIdx.x * 256 + threadIdx.x;
    if (t < N_NODES * F_HID) out[t] = v;
}

extern "C" void kernel_launch(void* const* d_in, const int* in_sizes, int n_in,
                              void* d_out, int out_size, void* d_ws, size_t ws_size,
                              hipStream_t stream) {
    const void* x   = d_in[0];
    const void* ei  = d_in[1];
    const void* W1  = d_in[2];
    const void* a1s = d_in[3];
    const void* a1d = d_in[4];
    const void* b1  = d_in[5];
    const void* W2  = d_in[6];
    const void* a2s = d_in[7];
    const void* a2d = d_in[8];
    const void* b2  = d_in[9];
    float* out = (float*)d_out;

    float* ws = (float*)d_ws;
    int*      flags  = (int*)(ws + WS_FLAGS);
    float*    adst   = ws + WS_ADST;
    float*    adst2  = ws + WS_ADST2;
    int*      bcnt   = (int*)(ws + WS_BCNT);
    int*      rowbeg = (int*)(ws + WS_ROWBEG);
    int*      rowcnt = (int*)(ws + WS_ROWCNT);
    unsigned* hc1    = (unsigned*)(ws + WS_HC1);
    unsigned* hc2    = (unsigned*)(ws + WS_HC2);
    int*      bedges = (int*)(ws + WS_BEDGES);
    int*      srcs   = (int*)(ws + WS_SRCS);

    const dim3 blk(256);
    const dim3 grdN((N_NODES + 255) / 256);
    const dim3 grdE((N_EDGES + 255) / 256);
    const dim3 grdO((N_NODES * F_HID + 255) / 256);
    const dim3 grdBF(GRDB + GRDN_F);
    const dim3 grdS(NBUCK);
    const dim3 grdA(N_NODES / 16);

    if (ws_size >= WS_BUCKET_END * 4) {
        k_probe0 <<<dim3(1), blk, 0, stream>>>(x, ei, flags, bcnt);
        k_binfeat<<<grdBF, dim3(1024), 0, stream>>>(ei, x, W1, a1s, a1d, flags,
                                                    bcnt, bedges, hc1, adst);
        k_bsort  <<<grdS, dim3(512), 0, stream>>>(bcnt, bedges, rowbeg, rowcnt, srcs);
        k_agg1   <<<grdA, blk, 0, stream>>>(rowbeg, rowcnt, srcs, adst, hc1,
                                            b1, W2, a2s, a2d, flags, hc2, adst2);
        k_agg2   <<<grdA, blk, 0, stream>>>(rowbeg, rowcnt, srcs, adst2, hc2,
                                            b2, flags, out);
    } else if (ws_size >= WS_ATOMIC_END * 4) {
        float* fb_h   = ws + WS_HC1;     // 1.6M fp32
        float* fb_acc = ws + WS_HC2;     // 1.6M fp32
        float* fb_den = ws + WS_FB_DEN;  // 100k
        float* fb_as  = ws + WS_FB_AS;   // 100k
        float* fb_ad  = ws + WS_ADST;
        k_probe0 <<<dim3(1), blk, 0, stream>>>(x, ei, flags, bcnt);
        k_feat1  <<<grdN, blk, 0, stream>>>(x, W1, a1s, a1d, flags, fb_h, fb_as, fb_ad);
        k_selfinit<<<grdO, blk, 0, stream>>>(fb_as, fb_ad, fb_h, fb_den, fb_acc);
        k_edge   <<<grdE, blk, 0, stream>>>(ei, flags, fb_as, fb_ad, fb_h, fb_den, fb_acc);
        k_div_elu<<<grdO, blk, 0, stream>>>(fb_acc, fb_den, b1, flags);
        k_mid    <<<grdN, blk, 0, stream>>>(fb_acc, W2, a2s, a2d, flags, fb_h, fb_as, fb_ad);
        k_selfinit<<<grdO, blk, 0, stream>>>(fb_as, fb_ad, fb_h, fb_den, fb_acc);
        k_edge   <<<grdE, blk, 0, stream>>>(ei, flags, fb_as, fb_ad, fb_h, fb_den, fb_acc);
        k_out    <<<grdO, blk, 0, stream>>>(fb_acc, fb_den, b2, flags, out);
    } else {
        k_diag<<<grdO, blk, 0, stream>>>(out, (float)(ws_size >> 10));
    }
}

// Round 13
// 294.588 us; speedup vs baseline: 1.0666x; 1.0666x over previous
//
#include <hip/hip_runtime.h>
#include <hip/hip_bf16.h>

typedef __hip_bfloat16 bf16;

static constexpr int N_NODES = 100000;
static constexpr int N_EDGES = 3200000;
static constexpr int F_IN    = 54;
static constexpr int F_HID   = 16;

// bucket/CSR path
static constexpr int BSHIFT    = 7;                  // 128 nodes per bucket
static constexpr int BNODES    = 128;
static constexpr int NBUCK     = (N_NODES + BNODES - 1) / BNODES;  // 782
static constexpr int CAP_B     = 5120;
static constexpr int BIN_CHUNK = 8192;
static constexpr int GRDB      = (N_EDGES + BIN_CHUNK - 1) / BIN_CHUNK;  // 391
static constexpr int GRDN_F    = (N_NODES + 1023) / 1024;                // 98

// ---------------------------------------------------------------------------
// ws layout (float indices) — identical to round-11 (proven).
// hc1/hc2: combined per-node 64-B rows, dword k = bf16(h[k]) | bf16(a_src)<<16.
// srcs stores BYTE offsets (src*64).
// ---------------------------------------------------------------------------
static constexpr size_t WS_FLAGS  = 0;        // 4 ints
static constexpr size_t WS_ADST   = 4;        // 100000
static constexpr size_t WS_ADST2  = 100004;   // 100000
static constexpr size_t WS_BCNT   = 200004;   // 1024 ints
static constexpr size_t WS_ROWBEG = 201028;   // 100000 ints
static constexpr size_t WS_ROWCNT = 301028;   // 100000 ints
static constexpr size_t WS_HC1    = 401028;   // 1,600,000 dw
static constexpr size_t WS_HC2    = 2001028;  // 1,600,000 dw
static constexpr size_t WS_BEDGES = 3601028;  // NBUCK*CAP_B ints
static constexpr size_t WS_SRCS   = 7604868;  // NBUCK*CAP_B ints
static constexpr size_t WS_BUCKET_END = WS_SRCS + (size_t)NBUCK * CAP_B; // 11,608,708
static constexpr size_t WS_FB_DEN     = 3601028;
static constexpr size_t WS_FB_AS      = 3701028;
static constexpr size_t WS_ATOMIC_END = 3801028;

__device__ __forceinline__ float lrelu(float v) { return fmaxf(v, 0.2f * v); }
__device__ __forceinline__ float loadf(const void* p, int i, bool f32) {
    return f32 ? ((const float*)p)[i] : __bfloat162float(((const bf16*)p)[i]);
}
__device__ __forceinline__ unsigned f2bf(float f) {   // RNE fp32->bf16 bits
    unsigned u = __float_as_uint(f);
    return (u + 0x7FFFu + ((u >> 16) & 1u)) >> 16;
}

// ---------------------------------------------------------------------------
// Probe (+ zero bcnt): bit0 = floats fp32 ; bit1 = edge_index int64
// ---------------------------------------------------------------------------
__global__ __launch_bounds__(256) void k_probe0(
    const void* __restrict__ x, const void* __restrict__ ei,
    int* __restrict__ flags, int* __restrict__ bcnt)
{
    __shared__ int cnt, nz;
    const int t = threadIdx.x;
    if (t == 0) { cnt = 0; nz = 0; }
    __syncthreads();
    const unsigned u = ((const unsigned*)x)[t];
    if ((u & 0x7FFFu) >= 0x4800u) atomicAdd(&cnt, 1);
    if (t < 64) {
        if (((const unsigned*)ei)[2 * t + 1] != 0u) atomicAdd(&nz, 1);
    }
    for (int i = t; i < 1024; i += 256) bcnt[i] = 0;
    __syncthreads();
    if (t == 0) flags[0] = ((cnt >= 16) ? 1 : 0) | ((nz == 0) ? 2 : 0);
}

// ---------------------------------------------------------------------------
// k_binfeat (1024 thr): [0,GRDB) bin w/ LDS edge cache; [GRDB,+GRDN_F) feat1:
// h1 = x@W1 (fp32 regs); emits combined row dword k = bf16(h[k])|bf16(a)<<16.
// ---------------------------------------------------------------------------
__global__ __launch_bounds__(1024, 8) void k_binfeat(
    const void* __restrict__ ei, const void* __restrict__ x,
    const void* __restrict__ W1, const void* __restrict__ a_s,
    const void* __restrict__ a_d, const int* __restrict__ flags,
    int* __restrict__ bcnt, int* __restrict__ bedges,
    unsigned* __restrict__ hc, float* __restrict__ adst)
{
    __shared__ int            hist[NBUCK];
    __shared__ int            base[NBUCK];
    __shared__ int            cval[BIN_CHUNK];
    __shared__ unsigned short cbkt[BIN_CHUNK];
    __shared__ float Wl[F_IN * F_HID];
    __shared__ float asl[F_HID];
    __shared__ float adl[F_HID];
    const int t = threadIdx.x;
    const bool f32 = flags[0] & 1;
    const bool i64 = flags[0] & 2;

    if (blockIdx.x < GRDB) {
        const int e0 = blockIdx.x * BIN_CHUNK;
        const int valid = min(BIN_CHUNK, N_EDGES - e0);
        for (int i = t; i < NBUCK; i += 1024) hist[i] = 0;
        __syncthreads();
#pragma unroll
        for (int i = 0; i < BIN_CHUNK / 1024; ++i) {
            const int idx = i * 1024 + t;
            const int e = e0 + idx;
            if (idx < valid) {
                int s, d;
                if (i64) {
                    s = ((const int*)ei)[2 * (size_t)e];
                    d = ((const int*)ei)[2 * ((size_t)N_EDGES + e)];
                } else {
                    s = ((const int*)ei)[e];
                    d = ((const int*)ei)[(size_t)N_EDGES + e];
                }
                const int b = d >> BSHIFT;
                cval[idx] = (s << BSHIFT) | (d & (BNODES - 1));
                cbkt[idx] = (unsigned short)b;
                atomicAdd(&hist[b], 1);
            }
        }
        __syncthreads();
        for (int i = t; i < NBUCK; i += 1024) {
            const int c = hist[i];
            base[i] = c ? atomicAdd(&bcnt[i], c) : 0;
            hist[i] = 0;
        }
        __syncthreads();
#pragma unroll
        for (int i = 0; i < BIN_CHUNK / 1024; ++i) {
            const int idx = i * 1024 + t;
            if (idx < valid) {
                const int b = cbkt[idx];
                const int r = atomicAdd(&hist[b], 1);
                const int pos = base[b] + r;
                if (pos < CAP_B) bedges[(size_t)b * CAP_B + pos] = cval[idx];
            }
        }
    } else {
        for (int i = t; i < F_IN * F_HID; i += 1024) Wl[i] = loadf(W1, i, f32);
        if (t < F_HID) { asl[t] = loadf(a_s, t, f32); adl[t] = loadf(a_d, t, f32); }
        __syncthreads();
        const int node = (blockIdx.x - GRDB) * 1024 + t;
        if (node >= N_NODES) return;

        float h[F_HID];
#pragma unroll
        for (int k = 0; k < F_HID; ++k) h[k] = 0.f;
        if (f32) {
            const float2* xp = (const float2*)((const float*)x + (size_t)node * F_IN);
#pragma unroll
            for (int j = 0; j < F_IN / 2; ++j) {
                const float2 v = xp[j];
#pragma unroll
                for (int k = 0; k < F_HID; ++k) {
                    h[k] = fmaf(v.x, Wl[(2*j)   * F_HID + k], h[k]);
                    h[k] = fmaf(v.y, Wl[(2*j+1) * F_HID + k], h[k]);
                }
            }
        } else {
            const unsigned* xu = (const unsigned*)x + (size_t)node * (F_IN / 2);
#pragma unroll
            for (int j = 0; j < F_IN / 2; ++j) {
                const unsigned u = xu[j];
                const float v0 = __uint_as_float(u << 16);
                const float v1 = __uint_as_float(u & 0xFFFF0000u);
#pragma unroll
                for (int k = 0; k < F_HID; ++k) {
                    h[k] = fmaf(v0, Wl[(2*j)   * F_HID + k], h[k]);
                    h[k] = fmaf(v1, Wl[(2*j+1) * F_HID + k], h[k]);
                }
            }
        }
        float s = 0.f, d = 0.f;
#pragma unroll
        for (int k = 0; k < F_HID; ++k) { s = fmaf(h[k], asl[k], s); d = fmaf(h[k], adl[k], d); }
        adst[node] = d;
        const unsigned ab = f2bf(s) << 16;
        unsigned pk[F_HID];
#pragma unroll
        for (int k = 0; k < F_HID; ++k) pk[k] = f2bf(h[k]) | ab;
        uint4* hb = (uint4*)(hc + (size_t)node * F_HID);
#pragma unroll
        for (int q = 0; q < 4; ++q)
            hb[q] = make_uint4(pk[4*q], pk[4*q+1], pk[4*q+2], pk[4*q+3]);
    }
}

// ---------------------------------------------------------------------------
// k_bsort (512 thr): per-bucket LDS counting sort into 16B-padded segments.
// srcs entries are pre-scaled BYTE offsets (src * 64).
// ---------------------------------------------------------------------------
__global__ __launch_bounds__(512) void k_bsort(
    const int* __restrict__ bcnt, const int* __restrict__ bedges,
    int* __restrict__ rowbeg, int* __restrict__ rowcnt, int* __restrict__ srcs)
{
    __shared__ int hist[BNODES];
    __shared__ int scan[BNODES];
    __shared__ int cur[BNODES];
    const int t = threadIdx.x;
    const int b = blockIdx.x;
    const int n0 = b << BSHIFT;
    if (t < BNODES) hist[t] = 0;
    __syncthreads();
    const int cnt = min(bcnt[b], CAP_B);
    const int* be = bedges + (size_t)b * CAP_B;
    for (int e = t; e < cnt; e += 512)
        atomicAdd(&hist[be[e] & (BNODES - 1)], 1);
    __syncthreads();
    if (t < BNODES) scan[t] = (hist[t] + 3) & ~3;
    __syncthreads();
#pragma unroll
    for (int off = 1; off < BNODES; off <<= 1) {
        const int v = (t < BNODES && t >= off) ? scan[t - off] : 0;
        __syncthreads();
        if (t < BNODES) scan[t] += v;
        __syncthreads();
    }
    if (t < BNODES) {
        const int ex = scan[t] - ((hist[t] + 3) & ~3);
        cur[t] = ex;
        const int node = n0 + t;
        if (node < N_NODES) {
            rowbeg[node] = b * CAP_B + ex;
            rowcnt[node] = hist[t];
        }
    }
    __syncthreads();
    for (int e = t; e < cnt; e += 512) {
        const int p = be[e];
        const int dl = p & (BNODES - 1);
        const int r = atomicAdd(&cur[dl], 1);
        if (r < CAP_B) srcs[(size_t)b * CAP_B + r] = (p >> BSHIFT) << 6;  // byte off
    }
}

// ---------------------------------------------------------------------------
// k_agg1: ONE WAVE PER NODE, 4 lanes per edge (lane = e*4+q; lane owns row
// quarter q = 4 features via one uint4 gather). One v_exp instruction covers
// 16 edges (vs 4 in the 16-lane layout) — ~2x fewer VALU instr/edge, no
// in-loop shuffles, no inter-group trip-count divergence. Once per node:
// butterfly-reduce over e, quad->feature transpose via 4 shuffles + cndmask,
// fused mid (z@W2) and layer-2 combined-row emit.
// ---------------------------------------------------------------------------
__global__ __launch_bounds__(256) void k_agg1(
    const int* __restrict__ rowbeg, const int* __restrict__ rowcnt,
    const int* __restrict__ srcs, const float* __restrict__ adst,
    const unsigned* __restrict__ hc, const void* __restrict__ b1,
    const void* __restrict__ W2, const void* __restrict__ a_s2,
    const void* __restrict__ a_d2, const int* __restrict__ flags,
    unsigned* __restrict__ hc2, float* __restrict__ adst2)
{
    __shared__ float Wl[F_HID * F_HID];
    __shared__ float asl[F_HID];
    __shared__ float adl[F_HID];
    __shared__ float bl[F_HID];
    const bool f32 = flags[0] & 1;
    const int t = threadIdx.x;
    if (t < F_HID * F_HID) Wl[t] = loadf(W2, t, f32);
    if (t < F_HID) {
        asl[t] = loadf(a_s2, t, f32);
        adl[t] = loadf(a_d2, t, f32);
        bl[t]  = loadf(b1, t, f32);
    }
    __syncthreads();

    const int lane = t & 63;
    const int e = lane >> 2, q = lane & 3;
    const int node = blockIdx.x * 4 + (t >> 6);     // 25000*4 = 100000 exact
    const float adn = adst[node];
    const int n = rowcnt[node];
    const int* sp = srcs + rowbeg[node];
    const char* basep = (const char*)hc + q * 16;   // + byte off = row quarter
    float4 acc = make_float4(0.f, 0.f, 0.f, 0.f);
    float denom = 0.f;
    for (int i = 0; i < n; i += 16) {
        const int ei = i + e;
        const unsigned off = (unsigned)sp[min(ei, n - 1)];
        const uint4 v = *(const uint4*)(basep + off);
        const float av = __uint_as_float(v.x & 0xFFFF0000u) + adn;
        float w = __expf(lrelu(av));
        w = (ei < n) ? w : 0.f;
        denom += w;
        acc.x = fmaf(w, __uint_as_float(v.x << 16), acc.x);
        acc.y = fmaf(w, __uint_as_float(v.y << 16), acc.y);
        acc.z = fmaf(w, __uint_as_float(v.z << 16), acc.z);
        acc.w = fmaf(w, __uint_as_float(v.w << 16), acc.w);
    }
    // butterfly over e (lane bits 2..5) -> every lane holds quad-q totals
#pragma unroll
    for (int o = 4; o < 64; o <<= 1) {
        acc.x += __shfl_xor(acc.x, o, 64);
        acc.y += __shfl_xor(acc.y, o, 64);
        acc.z += __shfl_xor(acc.z, o, 64);
        acc.w += __shfl_xor(acc.w, o, 64);
        denom += __shfl_xor(denom, o, 64);
    }
    // quad -> feature-k transpose: lane kk wants element (kk&3) of lane (kk>>2)
    const int kk = lane & 15;
    const float sx = __shfl(acc.x, kk >> 2, 64);
    const float sy = __shfl(acc.y, kk >> 2, 64);
    const float sz = __shfl(acc.z, kk >> 2, 64);
    const float sw = __shfl(acc.w, kk >> 2, 64);
    const int el = kk & 3;
    float accK = (el == 0) ? sx : (el == 1) ? sy : (el == 2) ? sz : sw;

    // self-loop + epilogue (meaningful on lanes 0..15; others compute junk)
    const unsigned vs = hc[(size_t)node * F_HID + kk];
    const float av0 = __uint_as_float(vs & 0xFFFF0000u) + adn;
    const float w0 = __expf(lrelu(av0));
    float z = (accK + w0 * __uint_as_float(vs << 16)) / (denom + w0) + bl[kk];
    z = z > 0.f ? z : expm1f(z);

    float hh = 0.f;
#pragma unroll
    for (int j = 0; j < F_HID; ++j) {
        const float zj = __shfl(z, j, 16);
        hh = fmaf(zj, Wl[j * F_HID + kk], hh);
    }
    float s2 = hh * asl[kk], d2 = hh * adl[kk];
#pragma unroll
    for (int o = 1; o < 16; o <<= 1) {
        s2 += __shfl_xor(s2, o, 16);
        d2 += __shfl_xor(d2, o, 16);
    }
    if (lane < 16) hc2[(size_t)node * F_HID + lane] = f2bf(hh) | (f2bf(s2) << 16);
    if (lane == 0) adst2[node] = d2;
}

// ---------------------------------------------------------------------------
// k_agg2: same wave-per-node quad-gather on layer-2 rows; writes fp32 out.
// ---------------------------------------------------------------------------
__global__ __launch_bounds__(256) void k_agg2(
    const int* __restrict__ rowbeg, const int* __restrict__ rowcnt,
    const int* __restrict__ srcs, const float* __restrict__ adst,
    const unsigned* __restrict__ hc, const void* __restrict__ b2,
    const int* __restrict__ flags, float* __restrict__ outp)
{
    const bool f32 = flags[0] & 1;
    const int t = threadIdx.x;
    const int lane = t & 63;
    const int e = lane >> 2, q = lane & 3;
    const int node = blockIdx.x * 4 + (t >> 6);
    const float adn = adst[node];
    const int n = rowcnt[node];
    const int* sp = srcs + rowbeg[node];
    const char* basep = (const char*)hc + q * 16;
    float4 acc = make_float4(0.f, 0.f, 0.f, 0.f);
    float denom = 0.f;
    for (int i = 0; i < n; i += 16) {
        const int ei = i + e;
        const unsigned off = (unsigned)sp[min(ei, n - 1)];
        const uint4 v = *(const uint4*)(basep + off);
        const float av = __uint_as_float(v.x & 0xFFFF0000u) + adn;
        float w = __expf(lrelu(av));
        w = (ei < n) ? w : 0.f;
        denom += w;
        acc.x = fmaf(w, __uint_as_float(v.x << 16), acc.x);
        acc.y = fmaf(w, __uint_as_float(v.y << 16), acc.y);
        acc.z = fmaf(w, __uint_as_float(v.z << 16), acc.z);
        acc.w = fmaf(w, __uint_as_float(v.w << 16), acc.w);
    }
#pragma unroll
    for (int o = 4; o < 64; o <<= 1) {
        acc.x += __shfl_xor(acc.x, o, 64);
        acc.y += __shfl_xor(acc.y, o, 64);
        acc.z += __shfl_xor(acc.z, o, 64);
        acc.w += __shfl_xor(acc.w, o, 64);
        denom += __shfl_xor(denom, o, 64);
    }
    const int kk = lane & 15;
    const float sx = __shfl(acc.x, kk >> 2, 64);
    const float sy = __shfl(acc.y, kk >> 2, 64);
    const float sz = __shfl(acc.z, kk >> 2, 64);
    const float sw = __shfl(acc.w, kk >> 2, 64);
    const int el = kk & 3;
    float accK = (el == 0) ? sx : (el == 1) ? sy : (el == 2) ? sz : sw;

    const unsigned vs = hc[(size_t)node * F_HID + kk];
    const float av0 = __uint_as_float(vs & 0xFFFF0000u) + adn;
    const float w0 = __expf(lrelu(av0));
    const float r = (accK + w0 * __uint_as_float(vs << 16)) / (denom + w0)
                    + loadf(b2, kk, f32);
    if (lane < 16) outp[(size_t)node * F_HID + lane] = r;
}

// ---------------------------------------------------------------------------
// Fallback kernels (round-3 proven atomic path, fp32 buffers) + diag
// ---------------------------------------------------------------------------
__global__ __launch_bounds__(256) void k_feat1(
    const void* __restrict__ x, const void* __restrict__ W1,
    const void* __restrict__ a_s, const void* __restrict__ a_d,
    const int* __restrict__ flags,
    float* __restrict__ hbuf, float* __restrict__ asrc, float* __restrict__ adst)
{
    const bool f32 = flags[0] & 1;
    __shared__ float Wl[F_IN * F_HID];
    __shared__ float asl[F_HID];
    __shared__ float adl[F_HID];
    const int t = threadIdx.x;
    for (int i = t; i < F_IN * F_HID; i += 256) Wl[i] = loadf(W1, i, f32);
    if (t < F_HID) { asl[t] = loadf(a_s, t, f32); adl[t] = loadf(a_d, t, f32); }
    __syncthreads();
    const int node = blockIdx.x * 256 + t;
    if (node >= N_NODES) return;
    float h[F_HID];
#pragma unroll
    for (int k = 0; k < F_HID; ++k) h[k] = 0.f;
    if (f32) {
        const float2* xp = (const float2*)((const float*)x + (size_t)node * F_IN);
#pragma unroll
        for (int j = 0; j < F_IN / 2; ++j) {
            const float2 v = xp[j];
#pragma unroll
            for (int k = 0; k < F_HID; ++k) {
                h[k] = fmaf(v.x, Wl[(2*j)   * F_HID + k], h[k]);
                h[k] = fmaf(v.y, Wl[(2*j+1) * F_HID + k], h[k]);
            }
        }
    } else {
        const unsigned* xu = (const unsigned*)x + (size_t)node * (F_IN / 2);
#pragma unroll
        for (int j = 0; j < F_IN / 2; ++j) {
            const unsigned u = xu[j];
            const float v0 = __uint_as_float(u << 16);
            const float v1 = __uint_as_float(u & 0xFFFF0000u);
#pragma unroll
            for (int k = 0; k < F_HID; ++k) {
                h[k] = fmaf(v0, Wl[(2*j)   * F_HID + k], h[k]);
                h[k] = fmaf(v1, Wl[(2*j+1) * F_HID + k], h[k]);
            }
        }
    }
    float s = 0.f, d = 0.f;
#pragma unroll
    for (int k = 0; k < F_HID; ++k) { s = fmaf(h[k], asl[k], s); d = fmaf(h[k], adl[k], d); }
    asrc[node] = s; adst[node] = d;
    float4* hb = (float4*)(hbuf + (size_t)node * F_HID);
#pragma unroll
    for (int q = 0; q < 4; ++q)
        hb[q] = make_float4(h[4*q], h[4*q+1], h[4*q+2], h[4*q+3]);
}

__global__ __launch_bounds__(256) void k_selfinit(
    const float* __restrict__ asrc, const float* __restrict__ adst,
    const float* __restrict__ h, float* __restrict__ denom, float* __restrict__ acc)
{
    const int t = blockIdx.x * 256 + threadIdx.x;
    if (t >= N_NODES * F_HID) return;
    const int n = t >> 4;
    const float w0 = __expf(lrelu(asrc[n] + adst[n]));
    if ((t & 15) == 0) denom[n] = w0;
    acc[t] = w0 * h[t];
}

__global__ __launch_bounds__(256) void k_edge(
    const void* __restrict__ ei, const int* __restrict__ flags,
    const float* __restrict__ asrc, const float* __restrict__ adst,
    const float* __restrict__ hbuf,
    float* __restrict__ denom, float* __restrict__ acc)
{
    const int e = blockIdx.x * 256 + threadIdx.x;
    if (e >= N_EDGES) return;
    int s, d;
    if (flags[0] & 2) {
        const long long* e64 = (const long long*)ei;
        s = (int)e64[e]; d = (int)e64[(size_t)N_EDGES + e];
    } else {
        const int* e32 = (const int*)ei;
        s = e32[e]; d = e32[(size_t)N_EDGES + e];
    }
    const float w = __expf(lrelu(asrc[s] + adst[d]));
    atomicAdd(&denom[d], w);
    const float4* hs = (const float4*)(hbuf + (size_t)s * F_HID);
    float* ad = acc + (size_t)d * F_HID;
#pragma unroll
    for (int q = 0; q < 4; ++q) {
        const float4 hv = hs[q];
        atomicAdd(ad + 4*q + 0, w * hv.x);
        atomicAdd(ad + 4*q + 1, w * hv.y);
        atomicAdd(ad + 4*q + 2, w * hv.z);
        atomicAdd(ad + 4*q + 3, w * hv.w);
    }
}

__global__ __launch_bounds__(256) void k_div_elu(
    float* __restrict__ acc, const float* __restrict__ denom,
    const void* __restrict__ b1, const int* __restrict__ flags)
{
    const bool f32 = flags[0] & 1;
    const int t = blockIdx.x * 256 + threadIdx.x;
    if (t >= N_NODES * F_HID) return;
    const float v = acc[t] / denom[t >> 4] + loadf(b1, t & 15, f32);
    acc[t] = v > 0.f ? v : expm1f(v);
}

__global__ __launch_bounds__(256) void k_mid(
    const float* __restrict__ z,
    const void* __restrict__ W2, const void* __restrict__ a_s2,
    const void* __restrict__ a_d2, const int* __restrict__ flags,
    float* __restrict__ h2, float* __restrict__ asrc, float* __restrict__ adst)
{
    const bool f32 = flags[0] & 1;
    __shared__ float Wl[F_HID * F_HID];
    __shared__ float asl[F_HID];
    __shared__ float adl[F_HID];
    const int t = threadIdx.x;
    if (t < F_HID * F_HID) Wl[t] = loadf(W2, t, f32);
    if (t < F_HID) { asl[t] = loadf(a_s2, t, f32); adl[t] = loadf(a_d2, t, f32); }
    __syncthreads();
    const int node = blockIdx.x * 256 + t;
    if (node >= N_NODES) return;
    float zr[F_HID];
    const float4* zi = (const float4*)(z + (size_t)node * F_HID);
#pragma unroll
    for (int q = 0; q < 4; ++q) {
        const float4 zv = zi[q];
        zr[4*q+0]=zv.x; zr[4*q+1]=zv.y; zr[4*q+2]=zv.z; zr[4*q+3]=zv.w;
    }
    float h[F_HID];
#pragma unroll
    for (int k = 0; k < F_HID; ++k) h[k] = 0.f;
#pragma unroll
    for (int j = 0; j < F_HID; ++j) {
        const float zv = zr[j];
#pragma unroll
        for (int k = 0; k < F_HID; ++k) h[k] = fmaf(zv, Wl[j * F_HID + k], h[k]);
    }
    float s = 0.f, d = 0.f;
#pragma unroll
    for (int k = 0; k < F_HID; ++k) { s = fmaf(h[k], asl[k], s); d = fmaf(h[k], adl[k], d); }
    asrc[node] = s; adst[node] = d;
    float4* hb = (float4*)(h2 + (size_t)node * F_HID);
#pragma unroll
    for (int q = 0; q < 4; ++q)
        hb[q] = make_float4(h[4*q], h[4*q+1], h[4*q+2], h[4*q+3]);
}

__global__ __launch_bounds__(256) void k_out(
    const float* __restrict__ acc, const float* __restrict__ denom,
    const void* __restrict__ b2, const int* __restrict__ flags,
    float* __restrict__ out)
{
    const bool f32 = flags[0] & 1;
    const int t = blockIdx.x * 256 + threadIdx.x;
    if (t >= N_NODES * F_HID) return;
    out[t] = acc[t] / denom[t >> 4] + loadf(b2, t & 15, f32);
}

__global__ __launch_bounds__(256) void k_diag(float* __restrict__ out, float v)
{
    const int t = blockIdx.x * 256 + threadIdx.x;
    if (t < N_NODES * F_HID) out[t] = v;
}

extern "C" void kernel_launch(void* const* d_in, const int* in_sizes, int n_in,
                              void* d_out, int out_size, void* d_ws, size_t ws_size,
                              hipStream_t stream) {
    const void* x   = d_in[0];
    const void* ei  = d_in[1];
    const void* W1  = d_in[2];
    const void* a1s = d_in[3];
    const void* a1d = d_in[4];
    const void* b1  = d_in[5];
    const void* W2  = d_in[6];
    const void* a2s = d_in[7];
    const void* a2d = d_in[8];
    const void* b2  = d_in[9];
    float* out = (float*)d_out;

    float* ws = (float*)d_ws;
    int*      flags  = (int*)(ws + WS_FLAGS);
    float*    adst   = ws + WS_ADST;
    float*    adst2  = ws + WS_ADST2;
    int*      bcnt   = (int*)(ws + WS_BCNT);
    int*      rowbeg = (int*)(ws + WS_ROWBEG);
    int*      rowcnt = (int*)(ws + WS_ROWCNT);
    unsigned* hc1    = (unsigned*)(ws + WS_HC1);
    unsigned* hc2    = (unsigned*)(ws + WS_HC2);
    int*      bedges = (int*)(ws + WS_BEDGES);
    int*      srcs   = (int*)(ws + WS_SRCS);

    const dim3 blk(256);
    const dim3 grdN((N_NODES + 255) / 256);
    const dim3 grdE((N_EDGES + 255) / 256);
    const dim3 grdO((N_NODES * F_HID + 255) / 256);
    const dim3 grdBF(GRDB + GRDN_F);
    const dim3 grdS(NBUCK);
    const dim3 grdA(N_NODES / 4);     // 25000 blocks, 1 wave per node

    if (ws_size >= WS_BUCKET_END * 4) {
        k_probe0 <<<dim3(1), blk, 0, stream>>>(x, ei, flags, bcnt);
        k_binfeat<<<grdBF, dim3(1024), 0, stream>>>(ei, x, W1, a1s, a1d, flags,
                                                    bcnt, bedges, hc1, adst);
        k_bsort  <<<grdS, dim3(512), 0, stream>>>(bcnt, bedges, rowbeg, rowcnt, srcs);
        k_agg1   <<<grdA, blk, 0, stream>>>(rowbeg, rowcnt, srcs, adst, hc1,
                                            b1, W2, a2s, a2d, flags, hc2, adst2);
        k_agg2   <<<grdA, blk, 0, stream>>>(rowbeg, rowcnt, srcs, adst2, hc2,
                                            b2, flags, out);
    } else if (ws_size >= WS_ATOMIC_END * 4) {
        float* fb_h   = ws + WS_HC1;     // 1.6M fp32
        float* fb_acc = ws + WS_HC2;     // 1.6M fp32
        float* fb_den = ws + WS_FB_DEN;  // 100k
        float* fb_as  = ws + WS_FB_AS;   // 100k
        float* fb_ad  = ws + WS_ADST;
        k_probe0 <<<dim3(1), blk, 0, stream>>>(x, ei, flags, bcnt);
        k_feat1  <<<grdN, blk, 0, stream>>>(x, W1, a1s, a1d, flags, fb_h, fb_as, fb_ad);
        k_selfinit<<<grdO, blk, 0, stream>>>(fb_as, fb_ad, fb_h, fb_den, fb_acc);
        k_edge   <<<grdE, blk, 0, stream>>>(ei, flags, fb_as, fb_ad, fb_h, fb_den, fb_acc);
        k_div_elu<<<grdO, blk, 0, stream>>>(fb_acc, fb_den, b1, flags);
        k_mid    <<<grdN, blk, 0, stream>>>(fb_acc, W2, a2s, a2d, flags, fb_h, fb_as, fb_ad);
        k_selfinit<<<grdO, blk, 0, stream>>>(fb_as, fb_ad, fb_h, fb_den, fb_acc);
        k_edge   <<<grdE, blk, 0, stream>>>(ei, flags, fb_as, fb_ad, fb_h, fb_den, fb_acc);
        k_out    <<<grdO, blk, 0, stream>>>(fb_acc, fb_den, b2, flags, out);
    } else {
        k_diag<<<grdO, blk, 0, stream>>>(out, (float)(ws_size >> 10));
    }
}

// Round 14
// 259.188 us; speedup vs baseline: 1.2123x; 1.1366x over previous
//
#include <hip/hip_runtime.h>
#include <hip/hip_bf16.h>

typedef __hip_bfloat16 bf16;

static constexpr int N_NODES = 100000;
static constexpr int N_EDGES = 3200000;
static constexpr int F_IN    = 54;
static constexpr int F_HID   = 16;

// bucket/CSR path
static constexpr int BSHIFT    = 7;                  // 128 nodes per bucket
static constexpr int BNODES    = 128;
static constexpr int NBUCK     = (N_NODES + BNODES - 1) / BNODES;  // 782
static constexpr int CAP_B     = 5120;
static constexpr int BIN_CHUNK = 8192;
static constexpr int GRDB      = (N_EDGES + BIN_CHUNK - 1) / BIN_CHUNK;  // 391
static constexpr int GRDN_F    = (N_NODES + 1023) / 1024;                // 98

// ---------------------------------------------------------------------------
// ws layout (float indices) — identical to round-11 (proven, 266 us).
// hc1/hc2: combined per-node 64-B rows, dword k = bf16(h[k]) | bf16(a_src)<<16
// -> ONE gather request per edge (lane k loads dword k of src row).
// ---------------------------------------------------------------------------
static constexpr size_t WS_FLAGS  = 0;        // 4 ints
static constexpr size_t WS_ADST   = 4;        // 100000
static constexpr size_t WS_ADST2  = 100004;   // 100000
static constexpr size_t WS_BCNT   = 200004;   // 1024 ints
static constexpr size_t WS_ROWBEG = 201028;   // 100000 ints
static constexpr size_t WS_ROWCNT = 301028;   // 100000 ints
static constexpr size_t WS_HC1    = 401028;   // 1,600,000 dw
static constexpr size_t WS_HC2    = 2001028;  // 1,600,000 dw
static constexpr size_t WS_BEDGES = 3601028;  // NBUCK*CAP_B ints
static constexpr size_t WS_SRCS   = 7604868;  // NBUCK*CAP_B ints
static constexpr size_t WS_BUCKET_END = WS_SRCS + (size_t)NBUCK * CAP_B; // 11,608,708
static constexpr size_t WS_FB_DEN     = 3601028;
static constexpr size_t WS_FB_AS      = 3701028;
static constexpr size_t WS_ATOMIC_END = 3801028;

__device__ __forceinline__ float lrelu(float v) { return fmaxf(v, 0.2f * v); }
__device__ __forceinline__ float loadf(const void* p, int i, bool f32) {
    return f32 ? ((const float*)p)[i] : __bfloat162float(((const bf16*)p)[i]);
}
__device__ __forceinline__ unsigned f2bf(float f) {   // RNE fp32->bf16 bits
    unsigned u = __float_as_uint(f);
    return (u + 0x7FFFu + ((u >> 16) & 1u)) >> 16;
}

// ---------------------------------------------------------------------------
// Probe (+ zero bcnt): bit0 = floats fp32 ; bit1 = edge_index int64
// ---------------------------------------------------------------------------
__global__ __launch_bounds__(256) void k_probe0(
    const void* __restrict__ x, const void* __restrict__ ei,
    int* __restrict__ flags, int* __restrict__ bcnt)
{
    __shared__ int cnt, nz;
    const int t = threadIdx.x;
    if (t == 0) { cnt = 0; nz = 0; }
    __syncthreads();
    const unsigned u = ((const unsigned*)x)[t];
    if ((u & 0x7FFFu) >= 0x4800u) atomicAdd(&cnt, 1);
    if (t < 64) {
        if (((const unsigned*)ei)[2 * t + 1] != 0u) atomicAdd(&nz, 1);
    }
    for (int i = t; i < 1024; i += 256) bcnt[i] = 0;
    __syncthreads();
    if (t == 0) flags[0] = ((cnt >= 16) ? 1 : 0) | ((nz == 0) ? 2 : 0);
}

// ---------------------------------------------------------------------------
// k_binfeat (1024 thr): [0,GRDB) bin w/ LDS edge cache; [GRDB,+GRDN_F) feat1:
// h1 = x@W1 (fp32 regs); emits combined row dword k = bf16(h[k])|bf16(a)<<16.
// ---------------------------------------------------------------------------
__global__ __launch_bounds__(1024, 8) void k_binfeat(
    const void* __restrict__ ei, const void* __restrict__ x,
    const void* __restrict__ W1, const void* __restrict__ a_s,
    const void* __restrict__ a_d, const int* __restrict__ flags,
    int* __restrict__ bcnt, int* __restrict__ bedges,
    unsigned* __restrict__ hc, float* __restrict__ adst)
{
    __shared__ int            hist[NBUCK];
    __shared__ int            base[NBUCK];
    __shared__ int            cval[BIN_CHUNK];
    __shared__ unsigned short cbkt[BIN_CHUNK];
    __shared__ float Wl[F_IN * F_HID];
    __shared__ float asl[F_HID];
    __shared__ float adl[F_HID];
    const int t = threadIdx.x;
    const bool f32 = flags[0] & 1;
    const bool i64 = flags[0] & 2;

    if (blockIdx.x < GRDB) {
        const int e0 = blockIdx.x * BIN_CHUNK;
        const int valid = min(BIN_CHUNK, N_EDGES - e0);
        for (int i = t; i < NBUCK; i += 1024) hist[i] = 0;
        __syncthreads();
#pragma unroll
        for (int i = 0; i < BIN_CHUNK / 1024; ++i) {
            const int idx = i * 1024 + t;
            const int e = e0 + idx;
            if (idx < valid) {
                int s, d;
                if (i64) {
                    s = ((const int*)ei)[2 * (size_t)e];
                    d = ((const int*)ei)[2 * ((size_t)N_EDGES + e)];
                } else {
                    s = ((const int*)ei)[e];
                    d = ((const int*)ei)[(size_t)N_EDGES + e];
                }
                const int b = d >> BSHIFT;
                cval[idx] = (s << BSHIFT) | (d & (BNODES - 1));
                cbkt[idx] = (unsigned short)b;
                atomicAdd(&hist[b], 1);
            }
        }
        __syncthreads();
        for (int i = t; i < NBUCK; i += 1024) {
            const int c = hist[i];
            base[i] = c ? atomicAdd(&bcnt[i], c) : 0;
            hist[i] = 0;
        }
        __syncthreads();
#pragma unroll
        for (int i = 0; i < BIN_CHUNK / 1024; ++i) {
            const int idx = i * 1024 + t;
            if (idx < valid) {
                const int b = cbkt[idx];
                const int r = atomicAdd(&hist[b], 1);
                const int pos = base[b] + r;
                if (pos < CAP_B) bedges[(size_t)b * CAP_B + pos] = cval[idx];
            }
        }
    } else {
        for (int i = t; i < F_IN * F_HID; i += 1024) Wl[i] = loadf(W1, i, f32);
        if (t < F_HID) { asl[t] = loadf(a_s, t, f32); adl[t] = loadf(a_d, t, f32); }
        __syncthreads();
        const int node = (blockIdx.x - GRDB) * 1024 + t;
        if (node >= N_NODES) return;

        float h[F_HID];
#pragma unroll
        for (int k = 0; k < F_HID; ++k) h[k] = 0.f;
        if (f32) {
            const float2* xp = (const float2*)((const float*)x + (size_t)node * F_IN);
#pragma unroll
            for (int j = 0; j < F_IN / 2; ++j) {
                const float2 v = xp[j];
#pragma unroll
                for (int k = 0; k < F_HID; ++k) {
                    h[k] = fmaf(v.x, Wl[(2*j)   * F_HID + k], h[k]);
                    h[k] = fmaf(v.y, Wl[(2*j+1) * F_HID + k], h[k]);
                }
            }
        } else {
            const unsigned* xu = (const unsigned*)x + (size_t)node * (F_IN / 2);
#pragma unroll
            for (int j = 0; j < F_IN / 2; ++j) {
                const unsigned u = xu[j];
                const float v0 = __uint_as_float(u << 16);
                const float v1 = __uint_as_float(u & 0xFFFF0000u);
#pragma unroll
                for (int k = 0; k < F_HID; ++k) {
                    h[k] = fmaf(v0, Wl[(2*j)   * F_HID + k], h[k]);
                    h[k] = fmaf(v1, Wl[(2*j+1) * F_HID + k], h[k]);
                }
            }
        }
        float s = 0.f, d = 0.f;
#pragma unroll
        for (int k = 0; k < F_HID; ++k) { s = fmaf(h[k], asl[k], s); d = fmaf(h[k], adl[k], d); }
        adst[node] = d;
        const unsigned ab = f2bf(s) << 16;
        unsigned pk[F_HID];
#pragma unroll
        for (int k = 0; k < F_HID; ++k) pk[k] = f2bf(h[k]) | ab;
        uint4* hb = (uint4*)(hc + (size_t)node * F_HID);
#pragma unroll
        for (int q = 0; q < 4; ++q)
            hb[q] = make_uint4(pk[4*q], pk[4*q+1], pk[4*q+2], pk[4*q+3]);
    }
}

// ---------------------------------------------------------------------------
// k_bsort (512 thr): per-bucket LDS counting sort into 16B-padded segments.
// ---------------------------------------------------------------------------
__global__ __launch_bounds__(512) void k_bsort(
    const int* __restrict__ bcnt, const int* __restrict__ bedges,
    int* __restrict__ rowbeg, int* __restrict__ rowcnt, int* __restrict__ srcs)
{
    __shared__ int hist[BNODES];
    __shared__ int scan[BNODES];
    __shared__ int cur[BNODES];
    const int t = threadIdx.x;
    const int b = blockIdx.x;
    const int n0 = b << BSHIFT;
    if (t < BNODES) hist[t] = 0;
    __syncthreads();
    const int cnt = min(bcnt[b], CAP_B);
    const int* be = bedges + (size_t)b * CAP_B;
    for (int e = t; e < cnt; e += 512)
        atomicAdd(&hist[be[e] & (BNODES - 1)], 1);
    __syncthreads();
    if (t < BNODES) scan[t] = (hist[t] + 3) & ~3;
    __syncthreads();
#pragma unroll
    for (int off = 1; off < BNODES; off <<= 1) {
        const int v = (t < BNODES && t >= off) ? scan[t - off] : 0;
        __syncthreads();
        if (t < BNODES) scan[t] += v;
        __syncthreads();
    }
    if (t < BNODES) {
        const int ex = scan[t] - ((hist[t] + 3) & ~3);
        cur[t] = ex;
        const int node = n0 + t;
        if (node < N_NODES) {
            rowbeg[node] = b * CAP_B + ex;
            rowcnt[node] = hist[t];
        }
    }
    __syncthreads();
    for (int e = t; e < cnt; e += 512) {
        const int p = be[e];
        const int dl = p & (BNODES - 1);
        const int r = atomicAdd(&cur[dl], 1);
        if (r < CAP_B) srcs[(size_t)b * CAP_B + r] = p >> BSHIFT;
    }
}

// ---------------------------------------------------------------------------
// k_agg1: r11-proven structure (16 lanes/node, one dword gather per edge,
// 8-unroll) + srcs software-pipelining (prefetch next int4 pair) + 4-tier.
// Epilogue fuses mid (z@W2 via width-16 shuffles) and emits layer-2 row.
// ---------------------------------------------------------------------------
__global__ __launch_bounds__(256) void k_agg1(
    const int* __restrict__ rowbeg, const int* __restrict__ rowcnt,
    const int* __restrict__ srcs, const float* __restrict__ adst,
    const unsigned* __restrict__ hc, const void* __restrict__ b1,
    const void* __restrict__ W2, const void* __restrict__ a_s2,
    const void* __restrict__ a_d2, const int* __restrict__ flags,
    unsigned* __restrict__ hc2, float* __restrict__ adst2)
{
    __shared__ float Wl[F_HID * F_HID];
    __shared__ float asl[F_HID];
    __shared__ float adl[F_HID];
    __shared__ float bl[F_HID];
    const bool f32 = flags[0] & 1;
    const int t = threadIdx.x;
    if (t < F_HID * F_HID) Wl[t] = loadf(W2, t, f32);
    if (t < F_HID) {
        asl[t] = loadf(a_s2, t, f32);
        adl[t] = loadf(a_d2, t, f32);
        bl[t]  = loadf(b1, t, f32);
    }
    __syncthreads();

    const int k = t & 15;
    const int node = blockIdx.x * 16 + (t >> 4);       // 6250*16 = 100000 exact
    const float adn = adst[node];
    const unsigned vs = hc[(size_t)node * F_HID + k];
    const float w0 = __expf(lrelu(__uint_as_float(vs & 0xFFFF0000u) + adn));
    float denom = w0;
    float acc = w0 * __uint_as_float(vs << 16);
    const int n = rowcnt[node];
    const int* sp = srcs + rowbeg[node];
    int i = 0;
    if (n >= 8) {
        int4 sa = *(const int4*)(sp);
        int4 sb = *(const int4*)(sp + 4);
        while (true) {
            const bool more = (i + 16 <= n);
            int4 na, nb;
            if (more) {                        // prefetch next 8 indices
                na = *(const int4*)(sp + i + 8);
                nb = *(const int4*)(sp + i + 12);
            }
            const unsigned v0 = hc[(size_t)sa.x * F_HID + k];
            const unsigned v1 = hc[(size_t)sa.y * F_HID + k];
            const unsigned v2 = hc[(size_t)sa.z * F_HID + k];
            const unsigned v3 = hc[(size_t)sa.w * F_HID + k];
            const unsigned v4 = hc[(size_t)sb.x * F_HID + k];
            const unsigned v5 = hc[(size_t)sb.y * F_HID + k];
            const unsigned v6 = hc[(size_t)sb.z * F_HID + k];
            const unsigned v7 = hc[(size_t)sb.w * F_HID + k];
            const float e0 = __expf(lrelu(__uint_as_float(v0 & 0xFFFF0000u) + adn));
            const float e1 = __expf(lrelu(__uint_as_float(v1 & 0xFFFF0000u) + adn));
            const float e2 = __expf(lrelu(__uint_as_float(v2 & 0xFFFF0000u) + adn));
            const float e3 = __expf(lrelu(__uint_as_float(v3 & 0xFFFF0000u) + adn));
            const float e4 = __expf(lrelu(__uint_as_float(v4 & 0xFFFF0000u) + adn));
            const float e5 = __expf(lrelu(__uint_as_float(v5 & 0xFFFF0000u) + adn));
            const float e6 = __expf(lrelu(__uint_as_float(v6 & 0xFFFF0000u) + adn));
            const float e7 = __expf(lrelu(__uint_as_float(v7 & 0xFFFF0000u) + adn));
            denom += (e0 + e1 + e2 + e3) + (e4 + e5 + e6 + e7);
            acc = fmaf(e0, __uint_as_float(v0 << 16), acc);
            acc = fmaf(e1, __uint_as_float(v1 << 16), acc);
            acc = fmaf(e2, __uint_as_float(v2 << 16), acc);
            acc = fmaf(e3, __uint_as_float(v3 << 16), acc);
            acc = fmaf(e4, __uint_as_float(v4 << 16), acc);
            acc = fmaf(e5, __uint_as_float(v5 << 16), acc);
            acc = fmaf(e6, __uint_as_float(v6 << 16), acc);
            acc = fmaf(e7, __uint_as_float(v7 << 16), acc);
            i += 8;
            if (!more) break;
            sa = na; sb = nb;
        }
    }
    if (i + 4 <= n) {
        const int4 sa = *(const int4*)(sp + i);
        const unsigned v0 = hc[(size_t)sa.x * F_HID + k];
        const unsigned v1 = hc[(size_t)sa.y * F_HID + k];
        const unsigned v2 = hc[(size_t)sa.z * F_HID + k];
        const unsigned v3 = hc[(size_t)sa.w * F_HID + k];
        const float e0 = __expf(lrelu(__uint_as_float(v0 & 0xFFFF0000u) + adn));
        const float e1 = __expf(lrelu(__uint_as_float(v1 & 0xFFFF0000u) + adn));
        const float e2 = __expf(lrelu(__uint_as_float(v2 & 0xFFFF0000u) + adn));
        const float e3 = __expf(lrelu(__uint_as_float(v3 & 0xFFFF0000u) + adn));
        denom += (e0 + e1) + (e2 + e3);
        acc = fmaf(e0, __uint_as_float(v0 << 16), acc);
        acc = fmaf(e1, __uint_as_float(v1 << 16), acc);
        acc = fmaf(e2, __uint_as_float(v2 << 16), acc);
        acc = fmaf(e3, __uint_as_float(v3 << 16), acc);
        i += 4;
    }
    for (; i < n; ++i) {
        const unsigned v = hc[(size_t)sp[i] * F_HID + k];
        const float w = __expf(lrelu(__uint_as_float(v & 0xFFFF0000u) + adn));
        denom += w;
        acc = fmaf(w, __uint_as_float(v << 16), acc);
    }
    float z = acc / denom + bl[k];
    z = z > 0.f ? z : expm1f(z);

    float hh = 0.f;
#pragma unroll
    for (int j = 0; j < F_HID; ++j) {
        const float zj = __shfl(z, j, 16);
        hh = fmaf(zj, Wl[j * F_HID + k], hh);
    }
    float s2 = hh * asl[k], d2 = hh * adl[k];
#pragma unroll
    for (int off = 1; off < 16; off <<= 1) {
        s2 += __shfl_xor(s2, off, 16);
        d2 += __shfl_xor(d2, off, 16);
    }
    hc2[(size_t)node * F_HID + k] = f2bf(hh) | (f2bf(s2) << 16);
    if (k == 0) adst2[node] = d2;
}

// ---------------------------------------------------------------------------
// k_agg2: same pipelined gather on layer-2 rows; writes fp32 out.
// ---------------------------------------------------------------------------
__global__ __launch_bounds__(256) void k_agg2(
    const int* __restrict__ rowbeg, const int* __restrict__ rowcnt,
    const int* __restrict__ srcs, const float* __restrict__ adst,
    const unsigned* __restrict__ hc, const void* __restrict__ b2,
    const int* __restrict__ flags, float* __restrict__ outp)
{
    const bool f32 = flags[0] & 1;
    const int t = threadIdx.x;
    const int k = t & 15;
    const int node = blockIdx.x * 16 + (t >> 4);
    const float adn = adst[node];
    const unsigned vs = hc[(size_t)node * F_HID + k];
    const float w0 = __expf(lrelu(__uint_as_float(vs & 0xFFFF0000u) + adn));
    float denom = w0;
    float acc = w0 * __uint_as_float(vs << 16);
    const int n = rowcnt[node];
    const int* sp = srcs + rowbeg[node];
    int i = 0;
    if (n >= 8) {
        int4 sa = *(const int4*)(sp);
        int4 sb = *(const int4*)(sp + 4);
        while (true) {
            const bool more = (i + 16 <= n);
            int4 na, nb;
            if (more) {
                na = *(const int4*)(sp + i + 8);
                nb = *(const int4*)(sp + i + 12);
            }
            const unsigned v0 = hc[(size_t)sa.x * F_HID + k];
            const unsigned v1 = hc[(size_t)sa.y * F_HID + k];
            const unsigned v2 = hc[(size_t)sa.z * F_HID + k];
            const unsigned v3 = hc[(size_t)sa.w * F_HID + k];
            const unsigned v4 = hc[(size_t)sb.x * F_HID + k];
            const unsigned v5 = hc[(size_t)sb.y * F_HID + k];
            const unsigned v6 = hc[(size_t)sb.z * F_HID + k];
            const unsigned v7 = hc[(size_t)sb.w * F_HID + k];
            const float e0 = __expf(lrelu(__uint_as_float(v0 & 0xFFFF0000u) + adn));
            const float e1 = __expf(lrelu(__uint_as_float(v1 & 0xFFFF0000u) + adn));
            const float e2 = __expf(lrelu(__uint_as_float(v2 & 0xFFFF0000u) + adn));
            const float e3 = __expf(lrelu(__uint_as_float(v3 & 0xFFFF0000u) + adn));
            const float e4 = __expf(lrelu(__uint_as_float(v4 & 0xFFFF0000u) + adn));
            const float e5 = __expf(lrelu(__uint_as_float(v5 & 0xFFFF0000u) + adn));
            const float e6 = __expf(lrelu(__uint_as_float(v6 & 0xFFFF0000u) + adn));
            const float e7 = __expf(lrelu(__uint_as_float(v7 & 0xFFFF0000u) + adn));
            denom += (e0 + e1 + e2 + e3) + (e4 + e5 + e6 + e7);
            acc = fmaf(e0, __uint_as_float(v0 << 16), acc);
            acc = fmaf(e1, __uint_as_float(v1 << 16), acc);
            acc = fmaf(e2, __uint_as_float(v2 << 16), acc);
            acc = fmaf(e3, __uint_as_float(v3 << 16), acc);
            acc = fmaf(e4, __uint_as_float(v4 << 16), acc);
            acc = fmaf(e5, __uint_as_float(v5 << 16), acc);
            acc = fmaf(e6, __uint_as_float(v6 << 16), acc);
            acc = fmaf(e7, __uint_as_float(v7 << 16), acc);
            i += 8;
            if (!more) break;
            sa = na; sb = nb;
        }
    }
    if (i + 4 <= n) {
        const int4 sa = *(const int4*)(sp + i);
        const unsigned v0 = hc[(size_t)sa.x * F_HID + k];
        const unsigned v1 = hc[(size_t)sa.y * F_HID + k];
        const unsigned v2 = hc[(size_t)sa.z * F_HID + k];
        const unsigned v3 = hc[(size_t)sa.w * F_HID + k];
        const float e0 = __expf(lrelu(__uint_as_float(v0 & 0xFFFF0000u) + adn));
        const float e1 = __expf(lrelu(__uint_as_float(v1 & 0xFFFF0000u) + adn));
        const float e2 = __expf(lrelu(__uint_as_float(v2 & 0xFFFF0000u) + adn));
        const float e3 = __expf(lrelu(__uint_as_float(v3 & 0xFFFF0000u) + adn));
        denom += (e0 + e1) + (e2 + e3);
        acc = fmaf(e0, __uint_as_float(v0 << 16), acc);
        acc = fmaf(e1, __uint_as_float(v1 << 16), acc);
        acc = fmaf(e2, __uint_as_float(v2 << 16), acc);
        acc = fmaf(e3, __uint_as_float(v3 << 16), acc);
        i += 4;
    }
    for (; i < n; ++i) {
        const unsigned v = hc[(size_t)sp[i] * F_HID + k];
        const float w = __expf(lrelu(__uint_as_float(v & 0xFFFF0000u) + adn));
        denom += w;
        acc = fmaf(w, __uint_as_float(v << 16), acc);
    }
    outp[(size_t)node * F_HID + k] = acc / denom + loadf(b2, k, f32);
}

// ---------------------------------------------------------------------------
// Fallback kernels (round-3 proven atomic path, fp32 buffers) + diag
// ---------------------------------------------------------------------------
__global__ __launch_bounds__(256) void k_feat1(
    const void* __restrict__ x, const void* __restrict__ W1,
    const void* __restrict__ a_s, const void* __restrict__ a_d,
    const int* __restrict__ flags,
    float* __restrict__ hbuf, float* __restrict__ asrc, float* __restrict__ adst)
{
    const bool f32 = flags[0] & 1;
    __shared__ float Wl[F_IN * F_HID];
    __shared__ float asl[F_HID];
    __shared__ float adl[F_HID];
    const int t = threadIdx.x;
    for (int i = t; i < F_IN * F_HID; i += 256) Wl[i] = loadf(W1, i, f32);
    if (t < F_HID) { asl[t] = loadf(a_s, t, f32); adl[t] = loadf(a_d, t, f32); }
    __syncthreads();
    const int node = blockIdx.x * 256 + t;
    if (node >= N_NODES) return;
    float h[F_HID];
#pragma unroll
    for (int k = 0; k < F_HID; ++k) h[k] = 0.f;
    if (f32) {
        const float2* xp = (const float2*)((const float*)x + (size_t)node * F_IN);
#pragma unroll
        for (int j = 0; j < F_IN / 2; ++j) {
            const float2 v = xp[j];
#pragma unroll
            for (int k = 0; k < F_HID; ++k) {
                h[k] = fmaf(v.x, Wl[(2*j)   * F_HID + k], h[k]);
                h[k] = fmaf(v.y, Wl[(2*j+1) * F_HID + k], h[k]);
            }
        }
    } else {
        const unsigned* xu = (const unsigned*)x + (size_t)node * (F_IN / 2);
#pragma unroll
        for (int j = 0; j < F_IN / 2; ++j) {
            const unsigned u = xu[j];
            const float v0 = __uint_as_float(u << 16);
            const float v1 = __uint_as_float(u & 0xFFFF0000u);
#pragma unroll
            for (int k = 0; k < F_HID; ++k) {
                h[k] = fmaf(v0, Wl[(2*j)   * F_HID + k], h[k]);
                h[k] = fmaf(v1, Wl[(2*j+1) * F_HID + k], h[k]);
            }
        }
    }
    float s = 0.f, d = 0.f;
#pragma unroll
    for (int k = 0; k < F_HID; ++k) { s = fmaf(h[k], asl[k], s); d = fmaf(h[k], adl[k], d); }
    asrc[node] = s; adst[node] = d;
    float4* hb = (float4*)(hbuf + (size_t)node * F_HID);
#pragma unroll
    for (int q = 0; q < 4; ++q)
        hb[q] = make_float4(h[4*q], h[4*q+1], h[4*q+2], h[4*q+3]);
}

__global__ __launch_bounds__(256) void k_selfinit(
    const float* __restrict__ asrc, const float* __restrict__ adst,
    const float* __restrict__ h, float* __restrict__ denom, float* __restrict__ acc)
{
    const int t = blockIdx.x * 256 + threadIdx.x;
    if (t >= N_NODES * F_HID) return;
    const int n = t >> 4;
    const float w0 = __expf(lrelu(asrc[n] + adst[n]));
    if ((t & 15) == 0) denom[n] = w0;
    acc[t] = w0 * h[t];
}

__global__ __launch_bounds__(256) void k_edge(
    const void* __restrict__ ei, const int* __restrict__ flags,
    const float* __restrict__ asrc, const float* __restrict__ adst,
    const float* __restrict__ hbuf,
    float* __restrict__ denom, float* __restrict__ acc)
{
    const int e = blockIdx.x * 256 + threadIdx.x;
    if (e >= N_EDGES) return;
    int s, d;
    if (flags[0] & 2) {
        const long long* e64 = (const long long*)ei;
        s = (int)e64[e]; d = (int)e64[(size_t)N_EDGES + e];
    } else {
        const int* e32 = (const int*)ei;
        s = e32[e]; d = e32[(size_t)N_EDGES + e];
    }
    const float w = __expf(lrelu(asrc[s] + adst[d]));
    atomicAdd(&denom[d], w);
    const float4* hs = (const float4*)(hbuf + (size_t)s * F_HID);
    float* ad = acc + (size_t)d * F_HID;
#pragma unroll
    for (int q = 0; q < 4; ++q) {
        const float4 hv = hs[q];
        atomicAdd(ad + 4*q + 0, w * hv.x);
        atomicAdd(ad + 4*q + 1, w * hv.y);
        atomicAdd(ad + 4*q + 2, w * hv.z);
        atomicAdd(ad + 4*q + 3, w * hv.w);
    }
}

__global__ __launch_bounds__(256) void k_div_elu(
    float* __restrict__ acc, const float* __restrict__ denom,
    const void* __restrict__ b1, const int* __restrict__ flags)
{
    const bool f32 = flags[0] & 1;
    const int t = blockIdx.x * 256 + threadIdx.x;
    if (t >= N_NODES * F_HID) return;
    const float v = acc[t] / denom[t >> 4] + loadf(b1, t & 15, f32);
    acc[t] = v > 0.f ? v : expm1f(v);
}

__global__ __launch_bounds__(256) void k_mid(
    const float* __restrict__ z,
    const void* __restrict__ W2, const void* __restrict__ a_s2,
    const void* __restrict__ a_d2, const int* __restrict__ flags,
    float* __restrict__ h2, float* __restrict__ asrc, float* __restrict__ adst)
{
    const bool f32 = flags[0] & 1;
    __shared__ float Wl[F_HID * F_HID];
    __shared__ float asl[F_HID];
    __shared__ float adl[F_HID];
    const int t = threadIdx.x;
    if (t < F_HID * F_HID) Wl[t] = loadf(W2, t, f32);
    if (t < F_HID) { asl[t] = loadf(a_s2, t, f32); adl[t] = loadf(a_d2, t, f32); }
    __syncthreads();
    const int node = blockIdx.x * 256 + t;
    if (node >= N_NODES) return;
    float zr[F_HID];
    const float4* zi = (const float4*)(z + (size_t)node * F_HID);
#pragma unroll
    for (int q = 0; q < 4; ++q) {
        const float4 zv = zi[q];
        zr[4*q+0]=zv.x; zr[4*q+1]=zv.y; zr[4*q+2]=zv.z; zr[4*q+3]=zv.w;
    }
    float h[F_HID];
#pragma unroll
    for (int k = 0; k < F_HID; ++k) h[k] = 0.f;
#pragma unroll
    for (int j = 0; j < F_HID; ++j) {
        const float zv = zr[j];
#pragma unroll
        for (int k = 0; k < F_HID; ++k) h[k] = fmaf(zv, Wl[j * F_HID + k], h[k]);
    }
    float s = 0.f, d = 0.f;
#pragma unroll
    for (int k = 0; k < F_HID; ++k) { s = fmaf(h[k], asl[k], s); d = fmaf(h[k], adl[k], d); }
    asrc[node] = s; adst[node] = d;
    float4* hb = (float4*)(h2 + (size_t)node * F_HID);
#pragma unroll
    for (int q = 0; q < 4; ++q)
        hb[q] = make_float4(h[4*q], h[4*q+1], h[4*q+2], h[4*q+3]);
}

__global__ __launch_bounds__(256) void k_out(
    const float* __restrict__ acc, const float* __restrict__ denom,
    const void* __restrict__ b2, const int* __restrict__ flags,
    float* __restrict__ out)
{
    const bool f32 = flags[0] & 1;
    const int t = blockIdx.x * 256 + threadIdx.x;
    if (t >= N_NODES * F_HID) return;
    out[t] = acc[t] / denom[t >> 4] + loadf(b2, t & 15, f32);
}

__global__ __launch_bounds__(256) void k_diag(float* __restrict__ out, float v)
{
    const int t = blockIdx.x * 256 + threadIdx.x;
    if (t < N_NODES * F_HID) out[t] = v;
}

extern "C" void kernel_launch(void* const* d_in, const int* in_sizes, int n_in,
                              void* d_out, int out_size, void* d_ws, size_t ws_size,
                              hipStream_t stream) {
    const void* x   = d_in[0];
    const void* ei  = d_in[1];
    const void* W1  = d_in[2];
    const void* a1s = d_in[3];
    const void* a1d = d_in[4];
    const void* b1  = d_in[5];
    const void* W2  = d_in[6];
    const void* a2s = d_in[7];
    const void* a2d = d_in[8];
    const void* b2  = d_in[9];
    float* out = (float*)d_out;

    float* ws = (float*)d_ws;
    int*      flags  = (int*)(ws + WS_FLAGS);
    float*    adst   = ws + WS_ADST;
    float*    adst2  = ws + WS_ADST2;
    int*      bcnt   = (int*)(ws + WS_BCNT);
    int*      rowbeg = (int*)(ws + WS_ROWBEG);
    int*      rowcnt = (int*)(ws + WS_ROWCNT);
    unsigned* hc1    = (unsigned*)(ws + WS_HC1);
    unsigned* hc2    = (unsigned*)(ws + WS_HC2);
    int*      bedges = (int*)(ws + WS_BEDGES);
    int*      srcs   = (int*)(ws + WS_SRCS);

    const dim3 blk(256);
    const dim3 grdN((N_NODES + 255) / 256);
    const dim3 grdE((N_EDGES + 255) / 256);
    const dim3 grdO((N_NODES * F_HID + 255) / 256);
    const dim3 grdBF(GRDB + GRDN_F);
    const dim3 grdS(NBUCK);
    const dim3 grdA(N_NODES / 16);

    if (ws_size >= WS_BUCKET_END * 4) {
        k_probe0 <<<dim3(1), blk, 0, stream>>>(x, ei, flags, bcnt);
        k_binfeat<<<grdBF, dim3(1024), 0, stream>>>(ei, x, W1, a1s, a1d, flags,
                                                    bcnt, bedges, hc1, adst);
        k_bsort  <<<grdS, dim3(512), 0, stream>>>(bcnt, bedges, rowbeg, rowcnt, srcs);
        k_agg1   <<<grdA, blk, 0, stream>>>(rowbeg, rowcnt, srcs, adst, hc1,
                                            b1, W2, a2s, a2d, flags, hc2, adst2);
        k_agg2   <<<grdA, blk, 0, stream>>>(rowbeg, rowcnt, srcs, adst2, hc2,
                                            b2, flags, out);
    } else if (ws_size >= WS_ATOMIC_END * 4) {
        float* fb_h   = ws + WS_HC1;     // 1.6M fp32
        float* fb_acc = ws + WS_HC2;     // 1.6M fp32
        float* fb_den = ws + WS_FB_DEN;  // 100k
        float* fb_as  = ws + WS_FB_AS;   // 100k
        float* fb_ad  = ws + WS_ADST;
        k_probe0 <<<dim3(1), blk, 0, stream>>>(x, ei, flags, bcnt);
        k_feat1  <<<grdN, blk, 0, stream>>>(x, W1, a1s, a1d, flags, fb_h, fb_as, fb_ad);
        k_selfinit<<<grdO, blk, 0, stream>>>(fb_as, fb_ad, fb_h, fb_den, fb_acc);
        k_edge   <<<grdE, blk, 0, stream>>>(ei, flags, fb_as, fb_ad, fb_h, fb_den, fb_acc);
        k_div_elu<<<grdO, blk, 0, stream>>>(fb_acc, fb_den, b1, flags);
        k_mid    <<<grdN, blk, 0, stream>>>(fb_acc, W2, a2s, a2d, flags, fb_h, fb_as, fb_ad);
        k_selfinit<<<grdO, blk, 0, stream>>>(fb_as, fb_ad, fb_h, fb_den, fb_acc);
        k_edge   <<<grdE, blk, 0, stream>>>(ei, flags, fb_as, fb_ad, fb_h, fb_den, fb_acc);
        k_out    <<<grdO, blk, 0, stream>>>(fb_acc, fb_den, b2, flags, out);
    } else {
        k_diag<<<grdO, blk, 0, stream>>>(out, (float)(ws_size >> 10));
    }
}